// Round 10
// baseline (96.318 us; speedup 1.0000x reference)
//
#include <hip/hip_runtime.h>
#include <cstdint>

#define CKDIM 128
#define MDIM  4096
#define QDIM  4096
#define BATCH 4

typedef __attribute__((ext_vector_type(8))) _Float16 half8;
typedef __attribute__((ext_vector_type(4))) float    f32x4;

#if __has_builtin(__builtin_amdgcn_exp2f)
#define EXP2(x) __builtin_amdgcn_exp2f(x)
#else
#define EXP2(x) exp2f(x)
#endif

#define ALPHA 0.12753139626596757f    // log2(e)/sqrt(128)
#define K2A   0.25506279253193514f    // 2*ALPHA

__device__ inline void gl_lds16(const void* g, void* l) {
    __builtin_amdgcn_global_load_lds(
        (const __attribute__((address_space(1))) unsigned*)g,
        (__attribute__((address_space(3))) unsigned*)l, 16, 0, 0);
}

// ---- 1) fused convert. Outputs CHUNKED layouts (conflict-free + linear-stage):
//   At: per batch, 128 m-tiles of 32 rows: [tile][c=k/8][m%32][8 halves] (8KB tiles)
//   Bt: per batch,  32 q-stripes of 128:   [stripe][c=k/8][q%128][8 halves] (32KB)
//   cm[b][m] = -ALPHA*sum_k Mk^2 (fp32-exact). Qk half zeroes sums[].
__global__ void convert_kernel(const float* __restrict__ Mk, const float* __restrict__ Qk,
                               _Float16* __restrict__ At, _Float16* __restrict__ Bt,
                               float* __restrict__ cm, float* __restrict__ sums) {
    __shared__ _Float16 T[128 * 130];
    __shared__ float    asqp[16][128];
    const int blk = blockIdx.x;                  // 256: mat(2) x b(4) x tile(32)
    const int mat = blk >> 7;
    const int b   = (blk >> 5) & 3;
    const int t   = blk & 31;                    // 128-row tile index
    const float* src = (mat ? Qk : Mk) + (size_t)b * CKDIM * MDIM + t * 128;
    const int tid = threadIdx.x;
    const int kg  = tid >> 4;
    const int ng  = tid & 15;

    float sq[8] = {0.f, 0.f, 0.f, 0.f, 0.f, 0.f, 0.f, 0.f};
    #pragma unroll
    for (int it = 0; it < 8; ++it) {
        int k = it * 16 + kg;
        const float* g = src + (size_t)k * MDIM + ng * 8;
        float4 v0 = *(const float4*)g;
        float4 v1 = *(const float4*)(g + 4);
        _Float16* p = &T[k * 130 + ng * 8];
        p[0] = (_Float16)v0.x; p[1] = (_Float16)v0.y; p[2] = (_Float16)v0.z; p[3] = (_Float16)v0.w;
        p[4] = (_Float16)v1.x; p[5] = (_Float16)v1.y; p[6] = (_Float16)v1.z; p[7] = (_Float16)v1.w;
        if (mat == 0) {
            sq[0] += v0.x * v0.x; sq[1] += v0.y * v0.y;
            sq[2] += v0.z * v0.z; sq[3] += v0.w * v0.w;
            sq[4] += v1.x * v1.x; sq[5] += v1.y * v1.y;
            sq[6] += v1.z * v1.z; sq[7] += v1.w * v1.w;
        }
    }
    if (mat == 0) {
        #pragma unroll
        for (int j = 0; j < 8; ++j) asqp[kg][ng * 8 + j] = sq[j];
    } else {
        if (tid < 128) sums[(blk & 127) * 128 + tid] = 0.f;
    }
    __syncthreads();
    // phase 2: gather k-column per (n, chunk) -> chunked layout, half8 stores
    #pragma unroll
    for (int it = 0; it < 8; ++it) {
        int idx = it * 256 + tid;                // 0..2047 = 16 c x 128 n
        int cc  = idx >> 7;                      // k-chunk 0..15
        int n   = idx & 127;                     // row within this 128-row tile
        half8 o;
        #pragma unroll
        for (int j = 0; j < 8; ++j) o[j] = T[(cc * 8 + j) * 130 + n];
        if (mat == 0) {
            // 32-row tiles: tile = t*4 + n/32
            _Float16* dst = At + (size_t)b * (MDIM * CKDIM)
                          + (size_t)(t * 4 + (n >> 5)) * 4096 + cc * 256 + (n & 31) * 8;
            *(half8*)dst = o;
        } else {
            // 128-q stripes: stripe = t
            _Float16* dst = Bt + (size_t)b * (QDIM * CKDIM)
                          + (size_t)t * 16384 + cc * 1024 + n * 8;
            *(half8*)dst = o;
        }
    }
    if (mat == 0 && tid < 128) {
        float s = 0.f;
        #pragma unroll
        for (int g = 0; g < 16; ++g) s += asqp[g][tid];
        cm[b * MDIM + t * 128 + tid] = -ALPHA * s;
    }
}

// ---- 2/3) GEMM passes. 1024 blocks (4/CU), 256 thr = 4 waves (1m x 4q).
// Per block: batch b, m-seg 512 (16 tiles of 32), q-stripe 128.
// B fragments live in VGPRs (global coalesced loads, no LDS). A staged in
// chunked 8KB tiles (linear gl_lds, conflict-free 256B-contiguous reads),
// double-buffered. WRITE=0: colsum atomics; WRITE=1: write exp/sum.
template <int WRITE>
__global__ __launch_bounds__(256, 4) void gemm_pass(
        const _Float16* __restrict__ At, const _Float16* __restrict__ Bt,
        const float* __restrict__ cmArr, float* __restrict__ sums,
        float* __restrict__ out) {
    __shared__ __align__(16) char ldsA[2][8192];
    const int tid  = threadIdx.x;
    const int lane = tid & 63;
    const int wv   = tid >> 6;      // q-group 0..3 (32 q each)
    const int g4   = lane >> 4;
    const int i    = lane & 15;

    const int wg = blockIdx.x;                      // 0..1023
    const int id = ((wg & 7) << 7) | (wg >> 3);     // XCD-chunked, bijective
    const int b  = id >> 8;
    const int qs = (id >> 3) & 31;
    const int ms = id & 7;
    const int q0 = qs << 7;
    const int m0 = ms << 9;

    const char* Ab = (const char*)At + ((size_t)(b * 128 + ms * 16) << 13);
    const char* Bb = (const char*)Bt + ((size_t)(b * 32 + qs) << 15);
    const int   cmb = (b << 12) + m0;

    // B fragments -> registers (coalesced 256B-per-16-lane-group loads)
    half8 bq[2][4];
    #pragma unroll
    for (int nf = 0; nf < 2; ++nf)
        #pragma unroll
        for (int t = 0; t < 4; ++t)
            bq[nf][t] = *(const half8*)(Bb + (t * 4 + g4) * 2048
                                           + (wv * 32 + nf * 16 + i) * 16);

    float rs0, rs1;
    if (WRITE) {
        rs0 = 1.0f / sums[(b << 12) + q0 + wv * 32 + i];
        rs1 = 1.0f / sums[(b << 12) + q0 + wv * 32 + 16 + i];
    }

    // stage A tile 0 (linear: LDS layout == global layout)
    {
        unsigned o0 = (unsigned)wv * 1024u;
        unsigned o1 = 4096u + (unsigned)wv * 1024u;
        gl_lds16(Ab + o0 + lane * 16, ldsA[0] + o0);
        gl_lds16(Ab + o1 + lane * 16, ldsA[0] + o1);
    }
    f32x4 cm0 = *(const f32x4*)&cmArr[cmb + g4 * 4];
    f32x4 cm1 = *(const f32x4*)&cmArr[cmb + 16 + g4 * 4];
    asm volatile("s_waitcnt vmcnt(0)" ::: "memory");
    __syncthreads();

    float cs0 = 0.f, cs1 = 0.f;

    #pragma unroll 1
    for (int mt = 0; mt < 16; ++mt) {
        const char* lA = ldsA[mt & 1];
        f32x4 cmn0, cmn1;
        if (mt + 1 < 16) {
            const char* Asrc = Ab + ((size_t)(mt + 1) << 13);
            char* dst = ldsA[(mt + 1) & 1];
            unsigned o0 = (unsigned)wv * 1024u;
            unsigned o1 = 4096u + (unsigned)wv * 1024u;
            gl_lds16(Asrc + o0 + lane * 16, dst + o0);
            gl_lds16(Asrc + o1 + lane * 16, dst + o1);
            cmn0 = *(const f32x4*)&cmArr[cmb + (mt + 1) * 32 + g4 * 4];
            cmn1 = *(const f32x4*)&cmArr[cmb + (mt + 1) * 32 + 16 + g4 * 4];
        }
        __builtin_amdgcn_sched_barrier(0);

        f32x4 acc[2][2] = {};
        #pragma unroll
        for (int t = 0; t < 4; ++t) {
            // chunk c = t*4+g4: each 16-lane group reads 256B contiguous
            const char* base = lA + (t * 4 + g4) * 512 + i * 16;
            half8 a0 = *(const half8*)(base);
            half8 a1 = *(const half8*)(base + 256);
            __builtin_amdgcn_s_setprio(1);
            acc[0][0] = __builtin_amdgcn_mfma_f32_16x16x32_f16(a0, bq[0][t], acc[0][0], 0, 0, 0);
            acc[0][1] = __builtin_amdgcn_mfma_f32_16x16x32_f16(a0, bq[1][t], acc[0][1], 0, 0, 0);
            acc[1][0] = __builtin_amdgcn_mfma_f32_16x16x32_f16(a1, bq[0][t], acc[1][0], 0, 0, 0);
            acc[1][1] = __builtin_amdgcn_mfma_f32_16x16x32_f16(a1, bq[1][t], acc[1][1], 0, 0, 0);
            __builtin_amdgcn_s_setprio(0);
        }

        if (WRITE) {
            #pragma unroll
            for (int mf = 0; mf < 2; ++mf) {
                f32x4  cmv  = mf ? cm1 : cm0;
                size_t mrow = (size_t)(m0 + mt * 32 + mf * 16 + g4 * 4);
                size_t base = ((((size_t)b << 12) + mrow) << 12) + (q0 + wv * 32 + i);
                #pragma unroll
                for (int r = 0; r < 4; ++r) {
                    out[base + ((size_t)r << 12)]      = EXP2(fmaf(acc[mf][0][r], K2A, cmv[r])) * rs0;
                    out[base + ((size_t)r << 12) + 16] = EXP2(fmaf(acc[mf][1][r], K2A, cmv[r])) * rs1;
                }
            }
        } else {
            #pragma unroll
            for (int mf = 0; mf < 2; ++mf) {
                f32x4 cmv = mf ? cm1 : cm0;
                #pragma unroll
                for (int r = 0; r < 4; ++r) {
                    cs0 += EXP2(fmaf(acc[mf][0][r], K2A, cmv[r]));
                    cs1 += EXP2(fmaf(acc[mf][1][r], K2A, cmv[r]));
                }
            }
        }

        if (mt + 1 < 16) {
            // oldest 2 outstanding VMEMs = the prefetch; leave cm(+stores) in flight
            if (WRITE) asm volatile("s_waitcnt vmcnt(18)" ::: "memory");
            else       asm volatile("s_waitcnt vmcnt(2)"  ::: "memory");
            __builtin_amdgcn_s_barrier();
            __builtin_amdgcn_sched_barrier(0);
        }
        cm0 = cmn0; cm1 = cmn1;
    }

    if (!WRITE) {
        cs0 += __shfl_xor(cs0, 16); cs0 += __shfl_xor(cs0, 32);
        cs1 += __shfl_xor(cs1, 16); cs1 += __shfl_xor(cs1, 32);
        if (lane < 16) {
            __hip_atomic_fetch_add(&sums[(b << 12) + q0 + wv * 32 + lane], cs0,
                                   __ATOMIC_RELAXED, __HIP_MEMORY_SCOPE_AGENT);
            __hip_atomic_fetch_add(&sums[(b << 12) + q0 + wv * 32 + 16 + lane], cs1,
                                   __ATOMIC_RELAXED, __HIP_MEMORY_SCOPE_AGENT);
        }
    }
}

extern "C" void kernel_launch(void* const* d_in, const int* in_sizes, int n_in,
                              void* d_out, int out_size, void* d_ws, size_t ws_size,
                              hipStream_t stream) {
    const float* Mk = (const float*)d_in[0];
    const float* Qk = (const float*)d_in[1];
    float* out = (float*)d_out;

    _Float16* At   = (_Float16*)d_ws;                               // 4 MB
    _Float16* Bt   = At + (size_t)BATCH * MDIM * CKDIM;             // 4 MB
    float*    sums = (float*)(Bt + (size_t)BATCH * MDIM * CKDIM);   // 64 KB
    float*    cm   = sums + BATCH * QDIM;                           // 64 KB

    convert_kernel<<<256, 256, 0, stream>>>(Mk, Qk, At, Bt, cm, sums);
    gemm_pass<0><<<1024, 256, 0, stream>>>(At, Bt, cm, sums, out);
    gemm_pass<1><<<1024, 256, 0, stream>>>(At, Bt, cm, sums, out);
}

// Round 11
// 84.874 us; speedup vs baseline: 1.1348x; 1.1348x over previous
//
#include <hip/hip_runtime.h>
#include <cstdint>

#define CKDIM 128
#define MDIM  4096
#define QDIM  4096
#define BATCH 4

typedef __attribute__((ext_vector_type(8)))  _Float16 half8;
typedef __attribute__((ext_vector_type(4)))  float    f32x4;
typedef __attribute__((ext_vector_type(16))) float    f32x16;

#if __has_builtin(__builtin_amdgcn_exp2f)
#define EXP2(x) __builtin_amdgcn_exp2f(x)
#else
#define EXP2(x) exp2f(x)
#endif

#define ALPHA 0.12753139626596757f    // log2(e)/sqrt(128)
#define K2A   0.25506279253193514f    // 2*ALPHA

__device__ inline void gl_lds16(const void* g, void* l) {
    __builtin_amdgcn_global_load_lds(
        (const __attribute__((address_space(1))) unsigned*)g,
        (__attribute__((address_space(3))) unsigned*)l, 16, 0, 0);
}

// ---- 1) fused convert. Chunked layouts (conflict-free + linear-stage):
//   At: per batch, 64 m-tiles of 64 rows: [tile][c=k/8][m%64][8 halves] (16KB)
//   Bt: per batch, 32 q-stripes of 128:   [stripe][c=k/8][q%128][8 halves] (32KB)
//   cm[b][m] = -ALPHA*sum_k Mk^2 (fp32-exact). Qk half zeroes sums[].
__global__ void convert_kernel(const float* __restrict__ Mk, const float* __restrict__ Qk,
                               _Float16* __restrict__ At, _Float16* __restrict__ Bt,
                               float* __restrict__ cm, float* __restrict__ sums) {
    __shared__ _Float16 T[128 * 130];
    __shared__ float    asqp[16][128];
    const int blk = blockIdx.x;                  // 256: mat(2) x b(4) x tile(32)
    const int mat = blk >> 7;
    const int b   = (blk >> 5) & 3;
    const int t   = blk & 31;                    // 128-row tile index
    const float* src = (mat ? Qk : Mk) + (size_t)b * CKDIM * MDIM + t * 128;
    const int tid = threadIdx.x;
    const int kg  = tid >> 4;
    const int ng  = tid & 15;

    float sq[8] = {0.f, 0.f, 0.f, 0.f, 0.f, 0.f, 0.f, 0.f};
    #pragma unroll
    for (int it = 0; it < 8; ++it) {
        int k = it * 16 + kg;
        const float* g = src + (size_t)k * MDIM + ng * 8;
        float4 v0 = *(const float4*)g;
        float4 v1 = *(const float4*)(g + 4);
        _Float16* p = &T[k * 130 + ng * 8];
        p[0] = (_Float16)v0.x; p[1] = (_Float16)v0.y; p[2] = (_Float16)v0.z; p[3] = (_Float16)v0.w;
        p[4] = (_Float16)v1.x; p[5] = (_Float16)v1.y; p[6] = (_Float16)v1.z; p[7] = (_Float16)v1.w;
        if (mat == 0) {
            sq[0] += v0.x * v0.x; sq[1] += v0.y * v0.y;
            sq[2] += v0.z * v0.z; sq[3] += v0.w * v0.w;
            sq[4] += v1.x * v1.x; sq[5] += v1.y * v1.y;
            sq[6] += v1.z * v1.z; sq[7] += v1.w * v1.w;
        }
    }
    if (mat == 0) {
        #pragma unroll
        for (int j = 0; j < 8; ++j) asqp[kg][ng * 8 + j] = sq[j];
    } else {
        if (tid < 128) sums[(blk & 127) * 128 + tid] = 0.f;
    }
    __syncthreads();
    #pragma unroll
    for (int it = 0; it < 8; ++it) {
        int idx = it * 256 + tid;                // 16 chunks x 128 rows
        int cc  = idx >> 7;
        int n   = idx & 127;
        half8 o;
        #pragma unroll
        for (int j = 0; j < 8; ++j) o[j] = T[(cc * 8 + j) * 130 + n];
        if (mat == 0) {
            // 64-row tiles: tile = t*2 + n/64, row = n%64
            _Float16* dst = At + (size_t)b * (MDIM * CKDIM)
                          + (size_t)(t * 2 + (n >> 6)) * 8192 + cc * 512 + (n & 63) * 8;
            *(half8*)dst = o;
        } else {
            _Float16* dst = Bt + (size_t)b * (QDIM * CKDIM)
                          + (size_t)t * 16384 + cc * 1024 + n * 8;
            *(half8*)dst = o;
        }
    }
    if (mat == 0 && tid < 128) {
        float s = 0.f;
        #pragma unroll
        for (int g = 0; g < 16; ++g) s += asqp[g][tid];
        cm[b * MDIM + t * 128 + tid] = -ALPHA * s;
    }
}

// ---- 2/3) GEMM passes, 32x32x16 MFMA. 1024 blocks (4/CU), 256 thr =
// 4 waves (2 m-groups x 2 q-groups). Block: b, m-seg 512 (8 tiles of 64),
// q-stripe 128. B frags (2 x 32 cols x full K) in VGPRs; A staged in chunked
// 16KB tiles (linear gl_lds, 512B-contiguous conflict-free reads), dbuf.
// One A-read feeds 2 MFMAs. WRITE=0: colsum atomics; WRITE=1: exp/sum out.
template <int WRITE>
__global__ __launch_bounds__(256, 4) void gemm_pass(
        const _Float16* __restrict__ At, const _Float16* __restrict__ Bt,
        const float* __restrict__ cmArr, float* __restrict__ sums,
        float* __restrict__ out) {
    __shared__ __align__(16) char ldsA[2][16384];
    const int tid  = threadIdx.x;
    const int lane = tid & 63;
    const int wv   = tid >> 6;      // 0..3
    const int mg   = wv >> 1;       // m-group (32 rows)
    const int qg   = wv & 1;        // q-group (64 cols)
    const int l5   = lane >> 5;     // 0..1
    const int l31  = lane & 31;

    const int wg = blockIdx.x;                      // 0..1023
    const int id = ((wg & 7) << 7) | (wg >> 3);     // XCD-chunked, bijective
    const int b  = id >> 8;
    const int qs = (id >> 3) & 31;
    const int ms = id & 7;
    const int q0 = qs << 7;
    const int m0 = ms << 9;

    const char* Ab = (const char*)At + ((size_t)(b * 64 + ms * 8) << 14);  // 16KB tiles
    const char* Bb = (const char*)Bt + ((size_t)(b * 32 + qs) << 15);      // 32KB stripe

    // B fragments -> registers: frag f covers cols qg*64+f*32+(l31);
    // k-step s (16 k): chunk 2s+l5, 512B-contiguous per 32-lane group.
    half8 bq0[8], bq1[8];
    #pragma unroll
    for (int s = 0; s < 8; ++s) {
        const char* p = Bb + (size_t)(2 * s + l5) * 2048 + (qg * 64 + l31) * 16;
        bq0[s] = *(const half8*)(p);
        bq1[s] = *(const half8*)(p + 512);      // +32 cols
    }

    float rs0, rs1;
    if (WRITE) {
        rs0 = 1.0f / sums[(b << 12) + q0 + qg * 64 + l31];
        rs1 = 1.0f / sums[(b << 12) + q0 + qg * 64 + 32 + l31];
    }

    // stage A tile 0 (linear: LDS layout == global layout)
    #pragma unroll
    for (int r = 0; r < 4; ++r) {
        unsigned Dw = r * 4096u + wv * 1024u;
        gl_lds16(Ab + Dw + lane * 16, ldsA[0] + Dw);
    }
    asm volatile("s_waitcnt vmcnt(0)" ::: "memory");
    __syncthreads();

    const int cmbase = (b << 12) + m0 + mg * 32 + l5 * 4;
    float cs0 = 0.f, cs1 = 0.f;

    #pragma unroll 1
    for (int mt = 0; mt < 8; ++mt) {
        const char* lA = ldsA[mt & 1];
        if (mt + 1 < 8) {
            const char* Asrc = Ab + ((size_t)(mt + 1) << 14);
            char* dst = ldsA[(mt + 1) & 1];
            #pragma unroll
            for (int r = 0; r < 4; ++r) {
                unsigned Dw = r * 4096u + wv * 1024u;
                gl_lds16(Asrc + Dw + lane * 16, dst + Dw);
            }
        }
        __builtin_amdgcn_sched_barrier(0);

        f32x16 acc0 = {}, acc1 = {};
        #pragma unroll
        for (int s = 0; s < 8; ++s) {
            // A frag: chunk 2s+l5, rows mg*32 + l31 -> 512B contiguous
            half8 a = *(const half8*)(lA + (2 * s + l5) * 1024 + (mg * 32 + l31) * 16);
            __builtin_amdgcn_s_setprio(1);
            acc0 = __builtin_amdgcn_mfma_f32_32x32x16_f16(a, bq0[s], acc0, 0, 0, 0);
            acc1 = __builtin_amdgcn_mfma_f32_32x32x16_f16(a, bq1[s], acc1, 0, 0, 0);
            __builtin_amdgcn_s_setprio(0);
        }

        // C/D: col = l31, row = (r&3) + 8*(r>>2) + 4*l5
        if (WRITE) {
            #pragma unroll
            for (int j = 0; j < 4; ++j) {
                f32x4 cmj = *(const f32x4*)&cmArr[cmbase + mt * 64 + j * 8];
                #pragma unroll
                for (int rr = 0; rr < 4; ++rr) {
                    int    row  = m0 + mt * 64 + mg * 32 + j * 8 + rr + l5 * 4;
                    size_t base = ((((size_t)b << 12) + row) << 12) + q0 + qg * 64 + l31;
                    out[base]      = EXP2(fmaf(acc0[j * 4 + rr], K2A, cmj[rr])) * rs0;
                    out[base + 32] = EXP2(fmaf(acc1[j * 4 + rr], K2A, cmj[rr])) * rs1;
                }
            }
        } else {
            #pragma unroll
            for (int j = 0; j < 4; ++j) {
                f32x4 cmj = *(const f32x4*)&cmArr[cmbase + mt * 64 + j * 8];
                #pragma unroll
                for (int rr = 0; rr < 4; ++rr) {
                    cs0 += EXP2(fmaf(acc0[j * 4 + rr], K2A, cmj[rr]));
                    cs1 += EXP2(fmaf(acc1[j * 4 + rr], K2A, cmj[rr]));
                }
            }
        }

        if (mt + 1 < 8) {
            // gate: drain everything older than {4 cm + (32 stores)} ->
            // the 4 prefetch gl_lds are guaranteed landed; stores stay async.
            if (WRITE) asm volatile("s_waitcnt vmcnt(36)" ::: "memory");
            else       asm volatile("s_waitcnt vmcnt(4)"  ::: "memory");
            __builtin_amdgcn_s_barrier();
            __builtin_amdgcn_sched_barrier(0);
        }
    }

    if (!WRITE) {
        cs0 += __shfl_xor(cs0, 32);
        cs1 += __shfl_xor(cs1, 32);
        if (lane < 32) {
            __hip_atomic_fetch_add(&sums[(b << 12) + q0 + qg * 64 + lane], cs0,
                                   __ATOMIC_RELAXED, __HIP_MEMORY_SCOPE_AGENT);
            __hip_atomic_fetch_add(&sums[(b << 12) + q0 + qg * 64 + 32 + lane], cs1,
                                   __ATOMIC_RELAXED, __HIP_MEMORY_SCOPE_AGENT);
        }
    }
}

extern "C" void kernel_launch(void* const* d_in, const int* in_sizes, int n_in,
                              void* d_out, int out_size, void* d_ws, size_t ws_size,
                              hipStream_t stream) {
    const float* Mk = (const float*)d_in[0];
    const float* Qk = (const float*)d_in[1];
    float* out = (float*)d_out;

    _Float16* At   = (_Float16*)d_ws;                               // 4 MB
    _Float16* Bt   = At + (size_t)BATCH * MDIM * CKDIM;             // 4 MB
    float*    sums = (float*)(Bt + (size_t)BATCH * MDIM * CKDIM);   // 64 KB
    float*    cm   = sums + BATCH * QDIM;                           // 64 KB

    convert_kernel<<<256, 256, 0, stream>>>(Mk, Qk, At, Bt, cm, sums);
    gemm_pass<0><<<1024, 256, 0, stream>>>(At, Bt, cm, sums, out);
    gemm_pass<1><<<1024, 256, 0, stream>>>(At, Bt, cm, sums, out);
}